// Round 1
// 592.692 us; speedup vs baseline: 1.5734x; 1.5734x over previous
//
#include <hip/hip_runtime.h>

#define NROWS  131072
#define ND     13
#define NS     26
#define NF     39
#define EMBD   16
#define DDIM   624      // 39*16
#define HIDN   32
#define VOCABN 100000
#define EPSF   1e-5f
#define NREP   64       // replica slots for global stat accumulation

// ---------------------------------------------------------------------------
// K1: per 16-row block.
//  - sparse gather: ALL 14 float4 loads issued back-to-back into registers
//    (A[7]/B[7]) before any use -> ~224B/lane in flight (latency hiding).
//  - dense-field compute sits between issue and consume to overlap latency.
//  - base[n] = first.sum + fm2 + bias
//  - phase B: y1 = deep @ Wl1 + bl1, REGISTER-TILED:
//      thread = (rg: 8-row group, c: 4-col quad, ds: interleaved d-chunk slice)
//      each Wl1 float4 read feeds 8 rows -> Wl1 L2 traffic 16x -> 2x
//      (10.2 GB -> 1.3 GB total). deep read from LDS (16-distinct-addr
//      broadcast pattern, conflict-free). ds-reduction via intra-wave shfl.
//  - stats: S1 (column sums) and M = y1^T y1 via per-block LDS tile +
//    replicated global atomics. k3 is then algebraic.
// ---------------------------------------------------------------------------
__global__ __launch_bounds__(256, 3) void k1_embed(
    const float* __restrict__ Xi_dense, const int* __restrict__ Xi_sparse,
    const float* __restrict__ Xv, const float* __restrict__ bias,
    const float* __restrict__ W1d, const float* __restrict__ b1d,
    const float* __restrict__ T1,
    const float* __restrict__ W2d, const float* __restrict__ b2d,
    const float* __restrict__ T2,
    const float* __restrict__ Wl1, const float* __restrict__ bl1,
    float* __restrict__ base, float* __restrict__ y1,
    float* __restrict__ S1rep, float* __restrict__ Mrep)
{
    __shared__ float4 deep4[16 * 156];    // 39936 B
    __shared__ float  xv_s[16 * NF];
    __shared__ int    xs_s[16 * NS];
    __shared__ float  xd_s[16 * ND];
    __shared__ float  sden[16][16];
    __shared__ float  ys[16][HIDN];       // y1 tile for M accumulation

    const int t  = threadIdx.x;
    const int n0 = blockIdx.x * 16;

    for (int i = t; i < 16 * NF; i += 256) xv_s[i] = Xv[n0 * NF + i];
    for (int i = t; i < 16 * NS; i += 256) xs_s[i] = Xi_sparse[n0 * NS + i];
    for (int i = t; i < 16 * ND; i += 256) xd_s[i] = Xi_dense[n0 * ND + i];
    __syncthreads();

    const int r = t >> 4;
    const int q = t & 15;
    const int n = n0 + r;
    float* drow = (float*)deep4 + r * DDIM;

    const int pp = q & 3;        // emb-part (positions 4pp..4pp+3)
    const int p4 = pp * 4;
    const int fb = q >> 2;       // field class mod 4

    // ---- issue ALL sparse gathers first (14 independent float4 loads) ----
    float4 A[7], B[7];
    float  xvv[7];
    #pragma unroll
    for (int i = 0; i < 7; ++i) {
        int  fs    = fb + 4 * i;
        bool valid = (fs < NS);
        int  fse   = valid ? fs : 0;
        xvv[i] = valid ? xv_s[r * NF + ND + fse] : 0.f;
        int ix  = xs_s[r * NS + fse];
        int off = (fse * VOCABN + ix) * EMBD + p4;
        A[i] = *(const float4*)(T1 + off);
        B[i] = *(const float4*)(T2 + off);
    }

    // ---- dense fields (overlaps the gather latency) ----
    float first_p = 0.f, ssq_p = 0.f, sq = 0.f;
    #pragma unroll
    for (int f = 0; f < ND; ++f) {
        float xv = xv_s[r * NF + f];
        float xd = xd_s[r * ND + f];
        float v1 = fmaf(xd, W1d[f * EMBD + q], b1d[f * EMBD + q]) * xv;
        float v2 = fmaf(xd, W2d[f * EMBD + q], b2d[f * EMBD + q]) * xv;
        first_p += v1;
        sq += v2;
        ssq_p = fmaf(v2, v2, ssq_p);
        drow[f * EMBD + q] = v2;
    }
    sden[r][q] = sq;

    // ---- consume gathers ----
    float4 s4 = make_float4(0.f, 0.f, 0.f, 0.f);
    #pragma unroll
    for (int i = 0; i < 7; ++i) {
        float  xv = xvv[i];
        float4 a  = A[i];
        float4 b  = B[i];
        first_p = fmaf(xv, (a.x + a.y) + (a.z + a.w), first_p);
        float4 v2 = make_float4(b.x * xv, b.y * xv, b.z * xv, b.w * xv);
        s4.x += v2.x; s4.y += v2.y; s4.z += v2.z; s4.w += v2.w;
        ssq_p = fmaf(v2.x, v2.x, ssq_p);
        ssq_p = fmaf(v2.y, v2.y, ssq_p);
        ssq_p = fmaf(v2.z, v2.z, ssq_p);
        ssq_p = fmaf(v2.w, v2.w, ssq_p);
        int fs = fb + 4 * i;
        if (fs < NS) deep4[r * 156 + (ND + fs) * 4 + pp] = v2;
    }

    // sum s4 over the 4 lanes sharing part pp (q, q^4, q^8, q^12: same row)
    s4.x += __shfl_xor(s4.x, 4, 64);  s4.y += __shfl_xor(s4.y, 4, 64);
    s4.z += __shfl_xor(s4.z, 4, 64);  s4.w += __shfl_xor(s4.w, 4, 64);
    s4.x += __shfl_xor(s4.x, 8, 64);  s4.y += __shfl_xor(s4.y, 8, 64);
    s4.z += __shfl_xor(s4.z, 8, 64);  s4.w += __shfl_xor(s4.w, 8, 64);

    __syncthreads();   // publish sden + deep4

    float4 sd = *(const float4*)(&sden[r][p4]);
    float sx = s4.x + sd.x, sy = s4.y + sd.y, sz = s4.z + sd.z, sw = s4.w + sd.w;
    float sdot = sx * sx + sy * sy + sz * sz + sw * sw;
    float contrib = first_p - 0.5f * ssq_p + ((q < 4) ? 0.5f * sdot : 0.f);
    contrib += __shfl_xor(contrib, 1, 64);
    contrib += __shfl_xor(contrib, 2, 64);
    contrib += __shfl_xor(contrib, 4, 64);
    contrib += __shfl_xor(contrib, 8, 64);
    if (q == 0) base[n] = contrib + bias[n];

    // ---- phase B: register-tiled GEMV -----------------------------------
    // thread t -> ds = t&15 (d-chunk slice, float4 chunks ds+16k),
    //             cB = 4-col quad (wave-derived), rgB = 8-row group.
    // Within a wave: ds spans 0..15 (lane bits 0..3), cB spans 4 values,
    // rgB is wave-uniform -> ds-reduction is pure intra-wave shfl.
    const int ds  = t & 15;
    const int cB  = ((t >> 6) & 1) * 4 + ((t >> 4) & 3);   // 0..7
    const int rgB = t >> 7;                                 // 0..1
    const float4* __restrict__ Wv4 = (const float4*)Wl1;    // [624][8] float4
    const float4* arow = deep4 + (rgB * 8) * 156;

    float4 acc[8];
    #pragma unroll
    for (int rr = 0; rr < 8; ++rr) acc[rr] = make_float4(0.f, 0.f, 0.f, 0.f);

    #pragma unroll 3
    for (int k = 0; k < 9; ++k) {
        const int ch = ds + 16 * k;          // float4 chunk index, < 144
        const int dbase = (4 * ch) * 8 + cB;
        float4 w0 = Wv4[dbase];
        float4 w1 = Wv4[dbase + 8];
        float4 w2 = Wv4[dbase + 16];
        float4 w3 = Wv4[dbase + 24];
        #pragma unroll
        for (int rr = 0; rr < 8; ++rr) {
            float4 a = arow[rr * 156 + ch];
            acc[rr].x = fmaf(a.x, w0.x, acc[rr].x); acc[rr].y = fmaf(a.x, w0.y, acc[rr].y);
            acc[rr].z = fmaf(a.x, w0.z, acc[rr].z); acc[rr].w = fmaf(a.x, w0.w, acc[rr].w);
            acc[rr].x = fmaf(a.y, w1.x, acc[rr].x); acc[rr].y = fmaf(a.y, w1.y, acc[rr].y);
            acc[rr].z = fmaf(a.y, w1.z, acc[rr].z); acc[rr].w = fmaf(a.y, w1.w, acc[rr].w);
            acc[rr].x = fmaf(a.z, w2.x, acc[rr].x); acc[rr].y = fmaf(a.z, w2.y, acc[rr].y);
            acc[rr].z = fmaf(a.z, w2.z, acc[rr].z); acc[rr].w = fmaf(a.z, w2.w, acc[rr].w);
            acc[rr].x = fmaf(a.w, w3.x, acc[rr].x); acc[rr].y = fmaf(a.w, w3.y, acc[rr].y);
            acc[rr].z = fmaf(a.w, w3.z, acc[rr].z); acc[rr].w = fmaf(a.w, w3.w, acc[rr].w);
        }
    }
    // tail: chunks 144..155 (12 chunks -> ds < 12)
    if (ds < 12) {
        const int ch = ds + 144;
        const int dbase = (4 * ch) * 8 + cB;
        float4 w0 = Wv4[dbase];
        float4 w1 = Wv4[dbase + 8];
        float4 w2 = Wv4[dbase + 16];
        float4 w3 = Wv4[dbase + 24];
        #pragma unroll
        for (int rr = 0; rr < 8; ++rr) {
            float4 a = arow[rr * 156 + ch];
            acc[rr].x = fmaf(a.x, w0.x, acc[rr].x); acc[rr].y = fmaf(a.x, w0.y, acc[rr].y);
            acc[rr].z = fmaf(a.x, w0.z, acc[rr].z); acc[rr].w = fmaf(a.x, w0.w, acc[rr].w);
            acc[rr].x = fmaf(a.y, w1.x, acc[rr].x); acc[rr].y = fmaf(a.y, w1.y, acc[rr].y);
            acc[rr].z = fmaf(a.y, w1.z, acc[rr].z); acc[rr].w = fmaf(a.y, w1.w, acc[rr].w);
            acc[rr].x = fmaf(a.z, w2.x, acc[rr].x); acc[rr].y = fmaf(a.z, w2.y, acc[rr].y);
            acc[rr].z = fmaf(a.z, w2.z, acc[rr].z); acc[rr].w = fmaf(a.z, w2.w, acc[rr].w);
            acc[rr].x = fmaf(a.w, w3.x, acc[rr].x); acc[rr].y = fmaf(a.w, w3.y, acc[rr].y);
            acc[rr].z = fmaf(a.w, w3.z, acc[rr].z); acc[rr].w = fmaf(a.w, w3.w, acc[rr].w);
        }
    }

    // reduce over the 16 ds-slices (lane bits 0..3) — intra-wave butterfly
    #pragma unroll
    for (int rr = 0; rr < 8; ++rr) {
        #pragma unroll
        for (int m = 1; m <= 8; m <<= 1) {
            acc[rr].x += __shfl_xor(acc[rr].x, m, 64);
            acc[rr].y += __shfl_xor(acc[rr].y, m, 64);
            acc[rr].z += __shfl_xor(acc[rr].z, m, 64);
            acc[rr].w += __shfl_xor(acc[rr].w, m, 64);
        }
    }

    if (ds == 0) {
        float4 bv = ((const float4*)bl1)[cB];
        #pragma unroll
        for (int rr = 0; rr < 8; ++rr) {
            const int row = rgB * 8 + rr;
            float4 v = acc[rr];
            v.x += bv.x; v.y += bv.y; v.z += bv.z; v.w += bv.w;
            ((float4*)(y1 + (size_t)(n0 + row) * HIDN))[cB] = v;
            *(float4*)&ys[row][4 * cB] = v;
        }
    }
    __syncthreads();   // publish ys

    // ---- stats: S1 (t<32) and M = ys^T ys (all 256 threads) ----
    const int rep = blockIdx.x & (NREP - 1);
    if (t < HIDN) {
        float s = 0.f;
        #pragma unroll
        for (int rr = 0; rr < 16; ++rr) s += ys[rr][t];
        atomicAdd(&S1rep[rep * HIDN + t], s);
    }
    {
        const int j1 = t >> 3;           // 0..31
        const int qd = t & 7;            // j2-quad 0..7
        float4 mp = make_float4(0.f, 0.f, 0.f, 0.f);
        #pragma unroll
        for (int rr = 0; rr < 16; ++rr) {
            float  a1 = ys[rr][j1];
            float4 b4 = *(const float4*)&ys[rr][qd * 4];
            mp.x = fmaf(a1, b4.x, mp.x);
            mp.y = fmaf(a1, b4.y, mp.y);
            mp.z = fmaf(a1, b4.z, mp.z);
            mp.w = fmaf(a1, b4.w, mp.w);
        }
        float* Md = &Mrep[rep * 1024 + t * 4];
        atomicAdd(Md + 0, mp.x);
        atomicAdd(Md + 1, mp.y);
        atomicAdd(Md + 2, mp.z);
        atomicAdd(Md + 3, mp.w);
    }
}

// ---------------------------------------------------------------------------
// K2: reduce S1/M replicas; BN1 fold; S2/Q2 closed-form from (S1, M);
//     BN2 fold; emit w[32], C.   y2 moments:  S2 = S1.V + N c,
//     Q2_j = V_j^T M V_j + 2 c_j (S1.V_j) + N c_j^2.
// ---------------------------------------------------------------------------
__global__ void k2_post(const float* __restrict__ S1rep, const float* __restrict__ Mrep,
                        const float* __restrict__ g1, const float* __restrict__ be1,
                        const float* __restrict__ Wl2, const float* __restrict__ bl2,
                        const float* __restrict__ g2, const float* __restrict__ be2,
                        float* __restrict__ wvec, float* __restrict__ Cc)
{
    __shared__ float Ms[1024], Vs[1024];
    __shared__ float S1s[HIDN], alpha[HIDN], beta[HIDN], cv[HIDN];
    __shared__ float gam[HIDN], cpart[HIDN];
    __shared__ float qpart[8][HIDN];
    const int t = threadIdx.x;

    {   // reduce M replicas
        float4 a4 = make_float4(0.f, 0.f, 0.f, 0.f);
        for (int rep = 0; rep < NREP; ++rep) {
            float4 v = ((const float4*)(Mrep + rep * 1024))[t];
            a4.x += v.x; a4.y += v.y; a4.z += v.z; a4.w += v.w;
        }
        ((float4*)Ms)[t] = a4;
    }
    if (t < HIDN) {
        float s = 0.f;
        for (int rep = 0; rep < NREP; ++rep) s += S1rep[rep * HIDN + t];
        S1s[t] = s;
    }
    __syncthreads();
    if (t < HIDN) {
        float m   = S1s[t] * (1.f / NROWS);
        float var = Ms[t * HIDN + t] * (1.f / NROWS) - m * m;
        float a   = g1[t] * rsqrtf(var + EPSF);
        alpha[t] = a;
        beta[t]  = be1[t] - a * m;
    }
    __syncthreads();
    for (int i = 0; i < 4; ++i) {
        int idx = t + 256 * i;
        Vs[idx] = alpha[idx >> 5] * Wl2[idx];
    }
    if (t < HIDN) {
        float c = bl2[t];
        for (int k = 0; k < HIDN; ++k) c = fmaf(beta[k], Wl2[k * HIDN + t], c);
        cv[t] = c;
    }
    __syncthreads();
    {   // quadratic form V_j^T M V_j, split over 8 k-groups
        const int j = t & 31, kg = t >> 5;
        float qp = 0.f;
        for (int kk = 0; kk < 4; ++kk) {
            int k = kg * 4 + kk;
            float u = 0.f;
            #pragma unroll
            for (int l = 0; l < HIDN; ++l) u = fmaf(Ms[k * HIDN + l], Vs[l * HIDN + j], u);
            qp = fmaf(Vs[k * HIDN + j], u, qp);
        }
        qpart[kg][j] = qp;
    }
    __syncthreads();
    if (t < HIDN) {
        float vmv = 0.f;
        #pragma unroll
        for (int g = 0; g < 8; ++g) vmv += qpart[g][t];
        float sv = 0.f;
        #pragma unroll
        for (int k = 0; k < HIDN; ++k) sv = fmaf(S1s[k], Vs[k * HIDN + t], sv);
        float S2 = sv + (float)NROWS * cv[t];
        float Q2 = vmv + 2.f * cv[t] * sv + (float)NROWS * cv[t] * cv[t];
        float m2 = S2 * (1.f / NROWS);
        float v2 = Q2 * (1.f / NROWS) - m2 * m2;
        float g  = g2[t] * rsqrtf(v2 + EPSF);
        gam[t]   = g;
        cpart[t] = g * (cv[t] - m2) + be2[t];
    }
    __syncthreads();
    if (t < HIDN) {
        float w = 0.f;
        #pragma unroll
        for (int j = 0; j < HIDN; ++j) w = fmaf(gam[j], Vs[t * HIDN + j], w);
        wvec[t] = w;
    }
    if (t == 0) {
        float C = 0.f;
        #pragma unroll
        for (int j = 0; j < HIDN; ++j) C += cpart[j];
        Cc[0] = C;
    }
}

// ---------------------------------------------------------------------------
// K5: out[n] = base[n] + dot(y1[n,:], w) + C
// ---------------------------------------------------------------------------
__global__ __launch_bounds__(256) void k5_final(
    const float* __restrict__ y1, const float* __restrict__ base,
    const float* __restrict__ wvec, const float* __restrict__ Cc,
    float* __restrict__ out)
{
    __shared__ float ws_s[HIDN];
    __shared__ float Cs;
    const int t = threadIdx.x;
    if (t < HIDN) ws_s[t] = wvec[t];
    if (t == 0) Cs = Cc[0];
    __syncthreads();
    const size_t n = (size_t)blockIdx.x * 256 + t;
    const float4* yv = (const float4*)(y1 + n * HIDN);
    float acc = base[n] + Cs;
    #pragma unroll
    for (int kk = 0; kk < 8; ++kk) {
        float4 v = yv[kk];
        acc = fmaf(v.x, ws_s[4 * kk + 0], acc);
        acc = fmaf(v.y, ws_s[4 * kk + 1], acc);
        acc = fmaf(v.z, ws_s[4 * kk + 2], acc);
        acc = fmaf(v.w, ws_s[4 * kk + 3], acc);
    }
    out[n] = acc;
}

extern "C" void kernel_launch(void* const* d_in, const int* in_sizes, int n_in,
                              void* d_out, int out_size, void* d_ws, size_t ws_size,
                              hipStream_t stream)
{
    const float* Xi_dense = (const float*)d_in[0];
    const int*   Xi_sparse= (const int*)  d_in[1];
    const float* Xv       = (const float*)d_in[2];
    const float* bias     = (const float*)d_in[3];
    const float* W1d      = (const float*)d_in[4];
    const float* b1d      = (const float*)d_in[5];
    const float* T1       = (const float*)d_in[6];
    const float* W2d      = (const float*)d_in[7];
    const float* b2d      = (const float*)d_in[8];
    const float* T2       = (const float*)d_in[9];
    const float* Wl1      = (const float*)d_in[10];
    const float* bl1      = (const float*)d_in[11];
    const float* g1       = (const float*)d_in[12];
    const float* be1      = (const float*)d_in[13];
    const float* Wl2      = (const float*)d_in[14];
    const float* bl2      = (const float*)d_in[15];
    const float* g2       = (const float*)d_in[16];
    const float* be2      = (const float*)d_in[17];
    float* out = (float*)d_out;

    // workspace layout (floats):
    // [0:2048)        S1rep  (64 x 32)
    // [2048:67584)    Mrep   (64 x 1024)
    // [67584:67616)   wvec
    // [67616]         C
    // [67840:+N)      base
    // [198912:+32N)   y1
    float* ws    = (float*)d_ws;
    float* S1rep = ws + 0;
    float* Mrep  = ws + 2048;
    float* wvec  = ws + 67584;
    float* Cc    = ws + 67616;
    float* base  = ws + 67840;
    float* y1    = ws + 198912;

    hipMemsetAsync(ws, 0, 67584 * sizeof(float), stream);

    k1_embed<<<NROWS / 16, 256, 0, stream>>>(Xi_dense, Xi_sparse, Xv, bias,
                                             W1d, b1d, T1, W2d, b2d, T2,
                                             Wl1, bl1, base, y1, S1rep, Mrep);
    k2_post<<<1, 256, 0, stream>>>(S1rep, Mrep, g1, be1, Wl2, bl2, g2, be2,
                                   wvec, Cc);
    k5_final<<<NROWS / 256, 256, 0, stream>>>(y1, base, wvec, Cc, out);
}

// Round 2
// 545.164 us; speedup vs baseline: 1.7106x; 1.0872x over previous
//
#include <hip/hip_runtime.h>

#define NROWS  131072
#define ND     13
#define NS     26
#define NF     39
#define EMBD   16
#define DDIM   624      // 39*16
#define HIDN   32
#define VOCABN 100000
#define EPSF   1e-5f
#define NREP   64       // replica slots for global stat accumulation
#define NTILES (NROWS / 16)      // 8192
#define GRIDK1 256               // persistent: 1 block per CU (LDS-bound)
#define TPBT   (NTILES / GRIDK1) // 32 tiles per block

// Raw barrier WITHOUT the vmcnt(0) drain __syncthreads would emit:
// LDS visibility only (lgkmcnt). Keeps the prefetched table gathers
// in flight across barriers — the whole point of the pipeline.
__device__ __forceinline__ void block_sync_lds() {
    asm volatile("s_waitcnt lgkmcnt(0)" ::: "memory");
    __builtin_amdgcn_s_barrier();
    __builtin_amdgcn_sched_barrier(0);
}

__device__ __forceinline__ void fma16(float4& acc, const float4 a,
                                      const float4 w0, const float4 w1,
                                      const float4 w2, const float4 w3)
{
    acc.x = fmaf(a.x, w0.x, acc.x); acc.y = fmaf(a.x, w0.y, acc.y);
    acc.z = fmaf(a.x, w0.z, acc.z); acc.w = fmaf(a.x, w0.w, acc.w);
    acc.x = fmaf(a.y, w1.x, acc.x); acc.y = fmaf(a.y, w1.y, acc.y);
    acc.z = fmaf(a.y, w1.z, acc.z); acc.w = fmaf(a.y, w1.w, acc.w);
    acc.x = fmaf(a.z, w2.x, acc.x); acc.y = fmaf(a.z, w2.y, acc.y);
    acc.z = fmaf(a.z, w2.z, acc.z); acc.w = fmaf(a.z, w2.w, acc.w);
    acc.x = fmaf(a.w, w3.x, acc.x); acc.y = fmaf(a.w, w3.y, acc.y);
    acc.z = fmaf(a.w, w3.z, acc.z); acc.w = fmaf(a.w, w3.w, acc.w);
}

// Phase-B one chunk: 4 swizzled w-reads + 8 row FMAs.
// Wl1 LDS swizzle: float4 (row d, colquad c) stored at slot c ^ (d&7)
// within the d-th 128B row -> 64 lanes spread uniformly over the 8
// 16B bank-phases (conflict-free minimum).
#define PHASEB_CHUNK(CH) {                                              \
    const int d0_ = (CH) << 2;                                          \
    const int sw_ = ((CH) & 1) << 2;                                    \
    float4 w0 = Wlds[(d0_    ) * 8 + (cB ^ (sw_ | 0))];                 \
    float4 w1 = Wlds[(d0_ + 1) * 8 + (cB ^ (sw_ | 1))];                 \
    float4 w2 = Wlds[(d0_ + 2) * 8 + (cB ^ (sw_ | 2))];                 \
    float4 w3 = Wlds[(d0_ + 3) * 8 + (cB ^ (sw_ | 3))];                 \
    _Pragma("unroll")                                                   \
    for (int rr = 0; rr < 8; ++rr) {                                    \
        float4 a = deep4[(rgB * 8 + rr) * 156 + (CH)];                  \
        fma16(acc[rr], a, w0, w1, w2, w3);                              \
    }                                                                   \
}

// ---------------------------------------------------------------------------
// K1, pipelined persistent version. Per block: 32 tiles of 16 rows.
// Per tile: dense -> consume gathers -> barrier -> ISSUE next tile's
// gathers -> phase B (pure LDS: swizzled Wl1 + deep4) -> barrier -> stats.
// Gathers stay in flight through all of phase B (raw barriers, no global
// consumption inside phase B) => ~80% gather duty cycle per wave.
// ---------------------------------------------------------------------------
__global__ __launch_bounds__(256, 1) void k1_embed(
    const float* __restrict__ Xi_dense, const int* __restrict__ Xi_sparse,
    const float* __restrict__ Xv, const float* __restrict__ bias,
    const float* __restrict__ W1d, const float* __restrict__ b1d,
    const float* __restrict__ T1,
    const float* __restrict__ W2d, const float* __restrict__ b2d,
    const float* __restrict__ T2,
    const float* __restrict__ Wl1, const float* __restrict__ bl1,
    float* __restrict__ base, float* __restrict__ y1,
    float* __restrict__ S1rep, float* __restrict__ Mrep)
{
    __shared__ float4 Wlds[DDIM * 8];     // 79872 B, swizzled Wl1
    __shared__ float4 deep4[16 * 156];    // 39936 B
    __shared__ float  ys[16][HIDN];       // 2048 B   (total 121856 B)

    const int t  = threadIdx.x;
    const int r  = t >> 4;
    const int q  = t & 15;
    const int pp = q & 3;
    const int p4 = pp * 4;
    const int fb = q >> 2;

    // phase-B mapping
    const int ds  = t & 15;                              // lane bits 0-3
    const int cB  = ((t >> 6) & 1) * 4 + ((t >> 4) & 3); // col quad 0..7
    const int rgB = t >> 7;                              // row group 0..1

    // ---- stage swizzled Wl1 into LDS ----
    for (int i = t; i < DDIM * 8; i += 256) {
        int d = i >> 3, c = i & 7;
        Wlds[(d << 3) | (c ^ (d & 7))] = ((const float4*)Wl1)[i];
    }

    // ---- dense-field W/b constants into registers (no vmem in dense) ----
    float w1r[ND], b1r[ND], w2r[ND], b2r[ND];
    #pragma unroll
    for (int f = 0; f < ND; ++f) {
        w1r[f] = W1d[f * EMBD + q]; b1r[f] = b1d[f * EMBD + q];
        w2r[f] = W2d[f * EMBD + q]; b2r[f] = b2d[f * EMBD + q];
    }
    const float4 blv = ((const float4*)bl1)[cB];

    // stats accumulators (one atomic per block at the end)
    float4 mpA = make_float4(0.f, 0.f, 0.f, 0.f);
    float  s1A = 0.f;
    const int j1 = t >> 3, qd = t & 7;

    // per-tile prefetched inputs (registers; issued BEFORE gathers so
    // their waits never drain the gathers)
    float xdv[ND], xvd[ND], xvs[7], biasr;
    int   idxr[7];
    float4 A[7], B[7];

    int tile = blockIdx.x;
    {   // PREFETCH tile 0 inputs
        const int n = tile * 16 + r;
        const int*   xsp = Xi_sparse + n * NS;
        const float* xvp = Xv + n * NF;
        const float* xdp = Xi_dense + n * ND;
        #pragma unroll
        for (int i2 = 0; i2 < 7; ++i2) {
            int fs = fb + 4 * i2; int fse = (fs < NS) ? fs : 0;
            idxr[i2] = xsp[fse];
            xvs[i2]  = (fs < NS) ? xvp[ND + fse] : 0.f;
        }
        #pragma unroll
        for (int f = 0; f < ND; ++f) { xdv[f] = xdp[f]; xvd[f] = xvp[f]; }
        biasr = bias[n];
    }
    block_sync_lds();    // Wlds published
    // ISSUE gathers for tile 0
    #pragma unroll
    for (int i2 = 0; i2 < 7; ++i2) {
        int fs = fb + 4 * i2; int fse = (fs < NS) ? fs : 0;
        int off = (fse * VOCABN + idxr[i2]) * EMBD + p4;
        A[i2] = *(const float4*)(T1 + off);
        B[i2] = *(const float4*)(T2 + off);
    }
    __builtin_amdgcn_sched_barrier(0);

    for (int it = 0; it < TPBT; ++it, tile += GRIDK1) {
        const int n = tile * 16 + r;
        float* drow = (float*)deep4 + r * DDIM;

        // ---- dense fields (registers + LDS only) ----
        float first_p = 0.f, ssq_p = 0.f, sq = 0.f;
        #pragma unroll
        for (int f = 0; f < ND; ++f) {
            float xv = xvd[f], xd = xdv[f];
            float v1 = fmaf(xd, w1r[f], b1r[f]) * xv;
            float v2 = fmaf(xd, w2r[f], b2r[f]) * xv;
            first_p += v1; sq += v2; ssq_p = fmaf(v2, v2, ssq_p);
            drow[f * EMBD + q] = v2;
        }
        // dense col-sums for part pp via intra-wave shuffle (lanes share r)
        const int lb = t & 48;
        float sdx = __shfl(sq, lb | (p4 + 0), 64);
        float sdy = __shfl(sq, lb | (p4 + 1), 64);
        float sdz = __shfl(sq, lb | (p4 + 2), 64);
        float sdw = __shfl(sq, lb | (p4 + 3), 64);

        // ---- consume gathers (first vmcnt wait on A/B: they've been in
        //      flight since mid-previous-tile) ----
        float4 s4 = make_float4(0.f, 0.f, 0.f, 0.f);
        #pragma unroll
        for (int i2 = 0; i2 < 7; ++i2) {
            float  xv = xvs[i2];
            float4 a  = A[i2];
            float4 b  = B[i2];
            first_p = fmaf(xv, (a.x + a.y) + (a.z + a.w), first_p);
            float4 v2 = make_float4(b.x * xv, b.y * xv, b.z * xv, b.w * xv);
            s4.x += v2.x; s4.y += v2.y; s4.z += v2.z; s4.w += v2.w;
            ssq_p = fmaf(v2.x, v2.x, ssq_p);
            ssq_p = fmaf(v2.y, v2.y, ssq_p);
            ssq_p = fmaf(v2.z, v2.z, ssq_p);
            ssq_p = fmaf(v2.w, v2.w, ssq_p);
            int fs = fb + 4 * i2;
            if (fs < NS) deep4[r * 156 + (ND + fs) * 4 + pp] = v2;
        }
        s4.x += __shfl_xor(s4.x, 4, 64);  s4.y += __shfl_xor(s4.y, 4, 64);
        s4.z += __shfl_xor(s4.z, 4, 64);  s4.w += __shfl_xor(s4.w, 4, 64);
        s4.x += __shfl_xor(s4.x, 8, 64);  s4.y += __shfl_xor(s4.y, 8, 64);
        s4.z += __shfl_xor(s4.z, 8, 64);  s4.w += __shfl_xor(s4.w, 8, 64);

        float sx = s4.x + sdx, sy = s4.y + sdy, sz = s4.z + sdz, sw = s4.w + sdw;
        float sdot = sx * sx + sy * sy + sz * sz + sw * sw;
        float contrib = first_p - 0.5f * ssq_p + ((q < 4) ? 0.5f * sdot : 0.f);
        contrib += __shfl_xor(contrib, 1, 64);
        contrib += __shfl_xor(contrib, 2, 64);
        contrib += __shfl_xor(contrib, 4, 64);
        contrib += __shfl_xor(contrib, 8, 64);
        if (q == 0) base[n] = contrib + biasr;

        const bool hasNext = (it + 1 < TPBT);
        if (hasNext) {   // PREFETCH next tile's inputs (idx first!)
            const int n2 = (tile + GRIDK1) * 16 + r;
            const int*   xsp = Xi_sparse + n2 * NS;
            const float* xvp = Xv + n2 * NF;
            const float* xdp = Xi_dense + n2 * ND;
            #pragma unroll
            for (int i2 = 0; i2 < 7; ++i2) {
                int fs = fb + 4 * i2; int fse = (fs < NS) ? fs : 0;
                idxr[i2] = xsp[fse];
                xvs[i2]  = (fs < NS) ? xvp[ND + fse] : 0.f;
            }
            #pragma unroll
            for (int f = 0; f < ND; ++f) { xdv[f] = xdp[f]; xvd[f] = xvp[f]; }
            biasr = bias[n2];
        }

        block_sync_lds();   // barrier1: deep4 tile published (no vmcnt drain)

        if (hasNext) {      // ISSUE next tile's gathers: in flight across
                            // the whole (pure-LDS) phase B below
            #pragma unroll
            for (int i2 = 0; i2 < 7; ++i2) {
                int fs = fb + 4 * i2; int fse = (fs < NS) ? fs : 0;
                int off = (fse * VOCABN + idxr[i2]) * EMBD + p4;
                A[i2] = *(const float4*)(T1 + off);
                B[i2] = *(const float4*)(T2 + off);
            }
        }
        __builtin_amdgcn_sched_barrier(0);

        // ---- phase B: y1 = deep @ Wl1, pure LDS + VALU ----
        float4 acc[8];
        #pragma unroll
        for (int rr = 0; rr < 8; ++rr) acc[rr] = make_float4(0.f, 0.f, 0.f, 0.f);

        #pragma unroll 3
        for (int k = 0; k < 9; ++k) {
            const int ch = ds + 16 * k;
            PHASEB_CHUNK(ch)
        }
        if (ds < 12) {            // tail chunks 144..155
            const int ch = ds + 144;
            PHASEB_CHUNK(ch)
        }

        // reduce over 16 ds slices (lane bits 0-3)
        #pragma unroll
        for (int rr = 0; rr < 8; ++rr) {
            #pragma unroll
            for (int m = 1; m <= 8; m <<= 1) {
                acc[rr].x += __shfl_xor(acc[rr].x, m, 64);
                acc[rr].y += __shfl_xor(acc[rr].y, m, 64);
                acc[rr].z += __shfl_xor(acc[rr].z, m, 64);
                acc[rr].w += __shfl_xor(acc[rr].w, m, 64);
            }
        }
        if (ds == 0) {
            #pragma unroll
            for (int rr = 0; rr < 8; ++rr) {
                const int row = rgB * 8 + rr;
                float4 v = acc[rr];
                v.x += blv.x; v.y += blv.y; v.z += blv.z; v.w += blv.w;
                ((float4*)(y1 + (size_t)(tile * 16 + row) * HIDN))[cB] = v;
                *(float4*)&ys[row][4 * cB] = v;
            }
        }
        block_sync_lds();   // barrier2: ys published (no vmcnt drain)

        // ---- stats accumulate into registers ----
        if (t < HIDN) {
            #pragma unroll
            for (int rr = 0; rr < 16; ++rr) s1A += ys[rr][t];
        }
        #pragma unroll
        for (int rr = 0; rr < 16; ++rr) {
            float  a1 = ys[rr][j1];
            float4 b4 = *(const float4*)&ys[rr][qd * 4];
            mpA.x = fmaf(a1, b4.x, mpA.x);
            mpA.y = fmaf(a1, b4.y, mpA.y);
            mpA.z = fmaf(a1, b4.z, mpA.z);
            mpA.w = fmaf(a1, b4.w, mpA.w);
        }
        // next iteration's dense writes hit deep4 (not ys): no extra barrier
    }

    // ---- one atomic flush per block ----
    const int rep = blockIdx.x & (NREP - 1);
    if (t < HIDN) atomicAdd(&S1rep[rep * HIDN + t], s1A);
    {
        float* Md = &Mrep[rep * 1024 + t * 4];
        atomicAdd(Md + 0, mpA.x);
        atomicAdd(Md + 1, mpA.y);
        atomicAdd(Md + 2, mpA.z);
        atomicAdd(Md + 3, mpA.w);
    }
}

// ---------------------------------------------------------------------------
// K2: reduce S1/M replicas; BN1 fold; S2/Q2 closed-form from (S1, M);
//     BN2 fold; emit w[32], C.
// ---------------------------------------------------------------------------
__global__ void k2_post(const float* __restrict__ S1rep, const float* __restrict__ Mrep,
                        const float* __restrict__ g1, const float* __restrict__ be1,
                        const float* __restrict__ Wl2, const float* __restrict__ bl2,
                        const float* __restrict__ g2, const float* __restrict__ be2,
                        float* __restrict__ wvec, float* __restrict__ Cc)
{
    __shared__ float Ms[1024], Vs[1024];
    __shared__ float S1s[HIDN], alpha[HIDN], beta[HIDN], cv[HIDN];
    __shared__ float gam[HIDN], cpart[HIDN];
    __shared__ float qpart[8][HIDN];
    const int t = threadIdx.x;

    {   // reduce M replicas
        float4 a4 = make_float4(0.f, 0.f, 0.f, 0.f);
        for (int rep = 0; rep < NREP; ++rep) {
            float4 v = ((const float4*)(Mrep + rep * 1024))[t];
            a4.x += v.x; a4.y += v.y; a4.z += v.z; a4.w += v.w;
        }
        ((float4*)Ms)[t] = a4;
    }
    if (t < HIDN) {
        float s = 0.f;
        for (int rep = 0; rep < NREP; ++rep) s += S1rep[rep * HIDN + t];
        S1s[t] = s;
    }
    __syncthreads();
    if (t < HIDN) {
        float m   = S1s[t] * (1.f / NROWS);
        float var = Ms[t * HIDN + t] * (1.f / NROWS) - m * m;
        float a   = g1[t] * rsqrtf(var + EPSF);
        alpha[t] = a;
        beta[t]  = be1[t] - a * m;
    }
    __syncthreads();
    for (int i = 0; i < 4; ++i) {
        int idx = t + 256 * i;
        Vs[idx] = alpha[idx >> 5] * Wl2[idx];
    }
    if (t < HIDN) {
        float c = bl2[t];
        for (int k = 0; k < HIDN; ++k) c = fmaf(beta[k], Wl2[k * HIDN + t], c);
        cv[t] = c;
    }
    __syncthreads();
    {   // quadratic form V_j^T M V_j, split over 8 k-groups
        const int j = t & 31, kg = t >> 5;
        float qp = 0.f;
        for (int kk = 0; kk < 4; ++kk) {
            int k = kg * 4 + kk;
            float u = 0.f;
            #pragma unroll
            for (int l = 0; l < HIDN; ++l) u = fmaf(Ms[k * HIDN + l], Vs[l * HIDN + j], u);
            qp = fmaf(Vs[k * HIDN + j], u, qp);
        }
        qpart[kg][j] = qp;
    }
    __syncthreads();
    if (t < HIDN) {
        float vmv = 0.f;
        #pragma unroll
        for (int g = 0; g < 8; ++g) vmv += qpart[g][t];
        float sv = 0.f;
        #pragma unroll
        for (int k = 0; k < HIDN; ++k) sv = fmaf(S1s[k], Vs[k * HIDN + t], sv);
        float S2 = sv + (float)NROWS * cv[t];
        float Q2 = vmv + 2.f * cv[t] * sv + (float)NROWS * cv[t] * cv[t];
        float m2 = S2 * (1.f / NROWS);
        float v2 = Q2 * (1.f / NROWS) - m2 * m2;
        float g  = g2[t] * rsqrtf(v2 + EPSF);
        gam[t]   = g;
        cpart[t] = g * (cv[t] - m2) + be2[t];
    }
    __syncthreads();
    if (t < HIDN) {
        float w = 0.f;
        #pragma unroll
        for (int j = 0; j < HIDN; ++j) w = fmaf(gam[j], Vs[t * HIDN + j], w);
        wvec[t] = w;
    }
    if (t == 0) {
        float C = 0.f;
        #pragma unroll
        for (int j = 0; j < HIDN; ++j) C += cpart[j];
        Cc[0] = C;
    }
}

// ---------------------------------------------------------------------------
// K5: out[n] = base[n] + dot(y1[n,:], w) + C
// ---------------------------------------------------------------------------
__global__ __launch_bounds__(256) void k5_final(
    const float* __restrict__ y1, const float* __restrict__ base,
    const float* __restrict__ wvec, const float* __restrict__ Cc,
    float* __restrict__ out)
{
    __shared__ float ws_s[HIDN];
    __shared__ float Cs;
    const int t = threadIdx.x;
    if (t < HIDN) ws_s[t] = wvec[t];
    if (t == 0) Cs = Cc[0];
    __syncthreads();
    const size_t n = (size_t)blockIdx.x * 256 + t;
    const float4* yv = (const float4*)(y1 + n * HIDN);
    float acc = base[n] + Cs;
    #pragma unroll
    for (int kk = 0; kk < 8; ++kk) {
        float4 v = yv[kk];
        acc = fmaf(v.x, ws_s[4 * kk + 0], acc);
        acc = fmaf(v.y, ws_s[4 * kk + 1], acc);
        acc = fmaf(v.z, ws_s[4 * kk + 2], acc);
        acc = fmaf(v.w, ws_s[4 * kk + 3], acc);
    }
    out[n] = acc;
}

extern "C" void kernel_launch(void* const* d_in, const int* in_sizes, int n_in,
                              void* d_out, int out_size, void* d_ws, size_t ws_size,
                              hipStream_t stream)
{
    const float* Xi_dense = (const float*)d_in[0];
    const int*   Xi_sparse= (const int*)  d_in[1];
    const float* Xv       = (const float*)d_in[2];
    const float* bias     = (const float*)d_in[3];
    const float* W1d      = (const float*)d_in[4];
    const float* b1d      = (const float*)d_in[5];
    const float* T1       = (const float*)d_in[6];
    const float* W2d      = (const float*)d_in[7];
    const float* b2d      = (const float*)d_in[8];
    const float* T2       = (const float*)d_in[9];
    const float* Wl1      = (const float*)d_in[10];
    const float* bl1      = (const float*)d_in[11];
    const float* g1       = (const float*)d_in[12];
    const float* be1      = (const float*)d_in[13];
    const float* Wl2      = (const float*)d_in[14];
    const float* bl2      = (const float*)d_in[15];
    const float* g2       = (const float*)d_in[16];
    const float* be2      = (const float*)d_in[17];
    float* out = (float*)d_out;

    // workspace layout (floats):
    // [0:2048)        S1rep  (64 x 32)
    // [2048:67584)    Mrep   (64 x 1024)
    // [67584:67616)   wvec
    // [67616]         C
    // [67840:+N)      base
    // [198912:+32N)   y1
    float* ws    = (float*)d_ws;
    float* S1rep = ws + 0;
    float* Mrep  = ws + 2048;
    float* wvec  = ws + 67584;
    float* Cc    = ws + 67616;
    float* base  = ws + 67840;
    float* y1    = ws + 198912;

    hipMemsetAsync(ws, 0, 67584 * sizeof(float), stream);

    k1_embed<<<GRIDK1, 256, 0, stream>>>(Xi_dense, Xi_sparse, Xv, bias,
                                         W1d, b1d, T1, W2d, b2d, T2,
                                         Wl1, bl1, base, y1, S1rep, Mrep);
    k2_post<<<1, 256, 0, stream>>>(S1rep, Mrep, g1, be1, Wl2, bl2, g2, be2,
                                   wvec, Cc);
    k5_final<<<NROWS / 256, 256, 0, stream>>>(y1, base, wvec, Cc, out);
}